// Round 6
// baseline (254.991 us; speedup 1.0000x reference)
//
#include <hip/hip_runtime.h>

namespace {

constexpr int H = 1024;
constexpr int W = 1024;
constexpr int PLANE = H * W;
constexpr int CIN = 18;     // total input channels
constexpr int C = 8;        // filterable channels
constexpr int TX = 16;
constexpr int TY = 16;
constexpr int SW = TX + 6;  // 22 halo tile width
constexpr int SH = TY + 6;  // 22 halo tile height
constexpr int NPOS = SW * SH;  // 484 positions

typedef _Float16 half2_t __attribute__((ext_vector_type(2)));
typedef _Float16 half8_t __attribute__((ext_vector_type(8)));

__device__ __forceinline__ float dot2acc(half2_t a, half2_t b, float c) {
#if defined(__has_builtin)
#if __has_builtin(__builtin_amdgcn_fdot2)
    return __builtin_amdgcn_fdot2(a, b, c, false);
#else
    return fmaf((float)a[0], (float)b[0], fmaf((float)a[1], (float)b[1], c));
#endif
#else
    return fmaf((float)a[0], (float)b[0], fmaf((float)a[1], (float)b[1], c));
#endif
}

template<bool INTERIOR>
__device__ __forceinline__ void run_tile(const float* __restrict__ inb,
                                         float* __restrict__ outb,
                                         half8_t* __restrict__ tile,
                                         float* __restrict__ msk,
                                         int gy0, int gx0)
{
    const int tx = threadIdx.x, ty = threadIdx.y;
    const int tid = ty * TX + tx;

    const int gy = gy0 + ty, gx = gx0 + tx;
    const int pofs = gy * W + gx;

    // ---- per-pixel params FIRST (before the barrier) so their global
    // latency overlaps the staging loop + barrier wait.
    half2_t rp01, rp23, rp45, rp67;
    float sx, sy;
    {
        const float* pp = inb + (size_t)C * PLANE + pofs;
        float r[C];
#pragma unroll
        for (int c = 0; c < C; ++c) {
            float p = pp[(size_t)c * PLANE];
            r[c] = -(p * p);
        }
        float px_ = pp[(size_t)8 * PLANE];
        float py_ = pp[(size_t)9 * PLANE];
        rp01 = half2_t{(_Float16)r[0], (_Float16)r[1]};
        rp23 = half2_t{(_Float16)r[2], (_Float16)r[3]};
        rp45 = half2_t{(_Float16)r[4], (_Float16)r[5]};
        rp67 = half2_t{(_Float16)r[6], (_Float16)r[7]};
        sx = -(px_ * px_);
        sy = -(py_ * py_);
    }

    // ---- stage: one 16B packed-f16 record per halo position ----
    for (int idx = tid; idx < NPOS; idx += TX * TY) {
        int y = idx / SW;
        int x = idx - y * SW;
        int sy_ = gy0 + y - 3;
        int sx_ = gx0 + x - 3;
        half8_t hv;
        if (INTERIOR || ((unsigned)sy_ < (unsigned)H && (unsigned)sx_ < (unsigned)W)) {
            const float* p = inb + sy_ * W + sx_;
#pragma unroll
            for (int c = 0; c < C; ++c) hv[c] = (_Float16)p[(size_t)c * PLANE];
            if (!INTERIOR) msk[idx] = 1.0f;
        } else {
#pragma unroll
            for (int c = 0; c < C; ++c) hv[c] = (_Float16)0.0f;
            msk[idx] = 0.0f;
        }
        tile[idx] = hv;
    }
    __syncthreads();

    const half8_t* lp = tile + ty * SW + tx;  // window origin for this pixel
    const half8_t fc = lp[3 * SW + 3];        // center (f16, so d==0 exactly)

    float acc0 = 0.f, acc1 = 0.f, acc2 = 0.f, ws = 0.f;
#pragma unroll
    for (int i = 0; i < 7; ++i) {
        const float ey = sy * (float)((i - 3) * (i - 3));  // 1 mul per row
        const half8_t* row = lp + i * SW;
        const float* mrow = msk + (ty + i) * SW + tx;
#pragma unroll
        for (int j = 0; j < 7; ++j) {
            half8_t q = row[j];                 // one ds_read_b128
            half8_t d = q - fc;                 // 4x v_pk_add_f16
            half8_t dd = d * d;                 // 4x v_pk_mul_f16
            // spatial init: dx^2 in {0,1,4,9} -> inline consts / hoisted sgpr
            float lw = fmaf(sx, (float)((j - 3) * (j - 3)), ey);
            lw = dot2acc(__builtin_shufflevector(dd, dd, 0, 1), rp01, lw);
            lw = dot2acc(__builtin_shufflevector(dd, dd, 2, 3), rp23, lw);
            lw = dot2acc(__builtin_shufflevector(dd, dd, 4, 5), rp45, lw);
            lw = dot2acc(__builtin_shufflevector(dd, dd, 6, 7), rp67, lw);
            // __expf: guaranteed v_mul_f32(log2e) + v_exp_f32 (no OCML
            // library fallback -- exp2f() could lower to a ~12-instr
            // range-reduction sequence, suspected fixed cost in R2-R5).
            float w = __expf(lw);
            if (!INTERIOR) w *= mrow[j];        // padding mask
            ws += w;
            acc0 = fmaf(w, (float)q[0], acc0);  // v_fma_mix_f32
            acc1 = fmaf(w, (float)q[1], acc1);
            acc2 = fmaf(w, (float)q[2], acc2);
        }
    }
    const float inv = 1.0f / ws;
    outb[pofs]             = acc0 * inv;
    outb[PLANE + pofs]     = acc1 * inv;
    outb[2 * PLANE + pofs] = acc2 * inv;
}

// launch_bounds (256,4): VGPR cap 128; this shape uses ~56-64, no spill.
// (256,8) forced 32 VGPRs -> 800MB scratch spill, 397us (R3). 2px/thread
// fully unrolled -> 1.7GB spill, 1117us (R4). Keep this shape.
__global__ __launch_bounds__(TX * TY, 4) void bilateral_kernel(const float* __restrict__ in,
                                                               float* __restrict__ out)
{
    __shared__ __align__(16) half8_t tile[NPOS];
    __shared__ float msk[NPOS];
    const int b = blockIdx.z;
    const int gx0 = blockIdx.x * TX;
    const int gy0 = blockIdx.y * TY;
    const float* inb = in + (size_t)b * CIN * PLANE;
    float* outb = out + (size_t)b * 3 * PLANE;

    const bool interior = (gx0 >= 3) && (gx0 + TX + 3 <= W) &&
                          (gy0 >= 3) && (gy0 + TY + 3 <= H);
    if (interior)
        run_tile<true>(inb, outb, tile, msk, gy0, gx0);
    else
        run_tile<false>(inb, outb, tile, msk, gy0, gx0);
}

} // namespace

extern "C" void kernel_launch(void* const* d_in, const int* in_sizes, int n_in,
                              void* d_out, int out_size, void* d_ws, size_t ws_size,
                              hipStream_t stream)
{
    const float* in = (const float*)d_in[0];
    float* out = (float*)d_out;
    dim3 grid(W / TX, H / TY, 2);
    dim3 block(TX, TY);
    hipLaunchKernelGGL(bilateral_kernel, grid, block, 0, stream, in, out);
}